// Round 12
// baseline (671.077 us; speedup 1.0000x reference)
//
#include <hip/hip_runtime.h>
#include <math.h>

#define B_ 2
#define N_ 1024
#define DIM_ 256
#define DEPTH_ 4
#define HEADS_ 4
#define DHEAD_ 64
#define INNER_ 256
#define SCALE_ 0.125f
#define STEP_ 0.1f
#define LAMBD_ 0.1f
#define EPS_ 1e-5f

typedef __attribute__((ext_vector_type(8))) short short8;
typedef __attribute__((ext_vector_type(4))) float f32x4;

// ---------------- bf16 split helpers ----------------
__device__ __forceinline__ unsigned short bf16_rne(float x) {
    unsigned u = __float_as_uint(x);
    unsigned r = (u + 0x7FFFu + ((u >> 16) & 1u)) >> 16;
    return (unsigned short)r;
}
__device__ __forceinline__ float bf16_tof(unsigned short h) {
    return __uint_as_float(((unsigned)h) << 16);
}
__device__ __forceinline__ void split2(float x, unsigned short& hi, unsigned short& lo) {
    hi = bf16_rne(x);
    lo = bf16_rne(x - bf16_tof(hi));
}
__device__ __forceinline__ f32x4 mfma16(short8 a, short8 b, f32x4 c) {
    return __builtin_amdgcn_mfma_f32_16x16x32_bf16(a, b, c, 0, 0, 0);
}
__device__ __forceinline__ short8 neg8(short8 v) {
    union { short8 s; unsigned u[4]; } a; a.s = v;
    a.u[0] ^= 0x80008000u; a.u[1] ^= 0x80008000u;
    a.u[2] ^= 0x80008000u; a.u[3] ^= 0x80008000u;
    return a.s;
}

// ---------------- complex layernorm: one wave per row, shfl-only reductions ----------------
__global__ __launch_bounds__(64)
void ln_kernel(const float* __restrict__ xr, const float* __restrict__ xi,
               const float* __restrict__ wr, const float* __restrict__ wi,
               const float* __restrict__ br, const float* __restrict__ bi,
               float* __restrict__ outr, float* __restrict__ outi,
               unsigned short* __restrict__ planes, int S) {
    int row = blockIdx.x;
    int lane = threadIdx.x;
    int base = row * DIM_ + lane * 4;

    float4 xr4 = *(const float4*)(xr + base);
    float4 xi4 = *(const float4*)(xi + base);
    float ar[4] = {xr4.x, xr4.y, xr4.z, xr4.w};
    float ai[4] = {xi4.x, xi4.y, xi4.z, xi4.w};

    float sr = ar[0] + ar[1] + ar[2] + ar[3];
    float si = ai[0] + ai[1] + ai[2] + ai[3];
#pragma unroll
    for (int o = 1; o < 64; o <<= 1) {
        sr += __shfl_xor(sr, o, 64);
        si += __shfl_xor(si, o, 64);
    }
    float mre = sr * (1.f / DIM_), mim = si * (1.f / DIM_);

    float drv[4], div[4];
    float vr = 0.f, vi = 0.f;
#pragma unroll
    for (int j = 0; j < 4; j++) {
        drv[j] = ar[j] - mre;
        div[j] = ai[j] - mim;
        vr += drv[j] * drv[j];
        vi += div[j] * div[j];
    }
#pragma unroll
    for (int o = 1; o < 64; o <<= 1) {
        vr += __shfl_xor(vr, o, 64);
        vi += __shfl_xor(vi, o, 64);
    }
    float c = vr * (1.f / DIM_) + EPS_;
    float d = vi * (1.f / DIM_);
    float r = sqrtf(c * c + d * d);
    float sre = sqrtf(0.5f * (r + c));
    float sim = sqrtf(fmaxf(0.5f * (r - c), 0.f));
    float inv = 1.f / r;

    int wc = lane * 4;
    float4 wr4 = *(const float4*)(wr + wc);
    float4 wi4 = *(const float4*)(wi + wc);
    float4 br4 = *(const float4*)(br + wc);
    float4 bi4 = *(const float4*)(bi + wc);
    float wrv[4] = {wr4.x, wr4.y, wr4.z, wr4.w};
    float wiv[4] = {wi4.x, wi4.y, wi4.z, wi4.w};
    float brv[4] = {br4.x, br4.y, br4.z, br4.w};
    float biv[4] = {bi4.x, bi4.y, bi4.z, bi4.w};

    float orr[4], oii[4];
    unsigned short rh[4], rl[4], ih[4], il[4];
#pragma unroll
    for (int j = 0; j < 4; j++) {
        float nr = (drv[j] * sre + div[j] * sim) * inv;
        float ni = (div[j] * sre - drv[j] * sim) * inv;
        orr[j] = wrv[j] * nr - wiv[j] * ni + brv[j];
        oii[j] = wrv[j] * ni + wiv[j] * nr + biv[j];
        split2(orr[j], rh[j], rl[j]);
        split2(oii[j], ih[j], il[j]);
    }
    *(float4*)(outr + base) = make_float4(orr[0], orr[1], orr[2], orr[3]);
    *(float4*)(outi + base) = make_float4(oii[0], oii[1], oii[2], oii[3]);
    *(ushort4*)(planes + 0 * (size_t)S + base) = make_ushort4(rh[0], rh[1], rh[2], rh[3]);
    *(ushort4*)(planes + 1 * (size_t)S + base) = make_ushort4(rl[0], rl[1], rl[2], rl[3]);
    *(ushort4*)(planes + 2 * (size_t)S + base) = make_ushort4(ih[0], ih[1], ih[2], ih[3]);
    *(ushort4*)(planes + 3 * (size_t)S + base) = make_ushort4(il[0], il[1], il[2], il[3]);
}

// ---------------- fused weight split (qkv + outw + ff in one dispatch) ----------------
__global__ void wsplit_all(const float* __restrict__ s0r, const float* __restrict__ s0i,
                           const float* __restrict__ s1r, const float* __restrict__ s1i,
                           const float* __restrict__ s2r, const float* __restrict__ s2i,
                           unsigned short* __restrict__ d0,
                           unsigned short* __restrict__ d1,
                           unsigned short* __restrict__ d2) {
    const int PER = DEPTH_ * 65536;
    int gid = blockIdx.x * 256 + threadIdx.x;
    int sel = gid / PER;
    int idx = gid - sel * PER;
    const float* wr = (sel == 0) ? s0r : (sel == 1) ? s1r : s2r;
    const float* wi = (sel == 0) ? s0i : (sel == 1) ? s1i : s2i;
    unsigned short* dst = (sel == 0) ? d0 : (sel == 1) ? d1 : d2;
    int l = idx >> 16, e = idx & 65535;
    unsigned short rh, rl, ih, il;
    split2(wr[idx], rh, rl);
    split2(wi[idx], ih, il);
    size_t base = (size_t)l * 4 * 65536;
    dst[base + 0 * 65536 + e] = rh;
    dst[base + 1 * 65536 + e] = rl;
    dst[base + 2 * 65536 + e] = ih;
    dst[base + 3 * 65536 + e] = il;
}

// ---------------- MFMA complex GEMM (unchanged) ----------------
template <int MODE>
__global__ __launch_bounds__(64)
void gemm_mfma(const unsigned short* __restrict__ Ap, int aStride,
               const unsigned short* __restrict__ Bp,
               unsigned short* __restrict__ wpo, unsigned short* __restrict__ wtpo,
               const float* __restrict__ biasR, const float* __restrict__ biasI,
               const float* resR, const float* resI,
               float* xoR, float* xoI, int S) {
    const int K = 256;
    int tileM = blockIdx.x * 16, tileN = blockIdx.y * 16;
    int lane = threadIdx.x;
    int m16 = lane & 15, quad = lane >> 4;

    f32x4 accP = (f32x4){0,0,0,0}, accN = (f32x4){0,0,0,0};
    f32x4 accIa = (f32x4){0,0,0,0}, accIb = (f32x4){0,0,0,0};

#pragma unroll
    for (int k0 = 0; k0 < 256; k0 += 32) {
        int kb = k0 + quad * 8;
        short8 a[4], b[4];
#pragma unroll
        for (int p = 0; p < 4; p++) {
            a[p] = *(const short8*)(Ap + (size_t)p * aStride + (size_t)(tileM + m16) * K + kb);
            b[p] = *(const short8*)(Bp + (size_t)p * 65536  + (size_t)(tileN + m16) * K + kb);
        }
        accP  = mfma16(a[0], b[0], accP);
        accP  = mfma16(a[0], b[1], accP);
        accP  = mfma16(a[1], b[0], accP);
        accN  = mfma16(a[2], b[2], accN);
        accN  = mfma16(a[2], b[3], accN);
        accN  = mfma16(a[3], b[2], accN);
        accIa = mfma16(a[0], b[2], accIa);
        accIa = mfma16(a[0], b[3], accIa);
        accIa = mfma16(a[1], b[2], accIa);
        accIb = mfma16(a[2], b[0], accIb);
        accIb = mfma16(a[2], b[1], accIb);
        accIb = mfma16(a[3], b[0], accIb);
    }

#pragma unroll
    for (int r = 0; r < 4; r++) {
        int row = tileM + quad * 4 + r;
        int col = tileN + m16;
        size_t g = (size_t)row * 256 + col;
        float vr = accP[r] - accN[r];
        float vi = accIa[r] + accIb[r];
        if (MODE == 1) {
            unsigned short h0, h1, h2, h3;
            split2(vr, h0, h1);
            split2(vi, h2, h3);
            size_t tidx = ((size_t)(row >> 10) * 256 + col) * 1024 + (row & 1023);
            wpo[0 * (size_t)S + g] = h0;
            wpo[1 * (size_t)S + g] = h1;
            wpo[2 * (size_t)S + g] = h2;
            wpo[3 * (size_t)S + g] = h3;
            wtpo[0 * (size_t)S + tidx] = h0;
            wtpo[1 * (size_t)S + tidx] = h1;
            wtpo[2 * (size_t)S + tidx] = h2;
            wtpo[3 * (size_t)S + tidx] = h3;
        } else if (MODE == 2) {
            xoR[g] = vr + biasR[col] + resR[g];
            xoI[g] = vi + biasI[col] + resI[g];
        } else {
            float zr = resR[g] + STEP_ * vr - STEP_ * LAMBD_;
            float zi = resI[g] + STEP_ * vi;
            xoR[g] = fmaxf(zr, 0.f);
            xoI[g] = fmaxf(zi, 0.f);
        }
    }
}

// ---------------- MFMA flash attention: split-K across blocks ----------------
// grid (B*H, N/16, 2), 256 threads. blockIdx.z = key half (8 tiles each);
// wave w handles kt = z*8 + w + 4t, t=0..1. id%8 = blockIdx.x -> XCD-local K/V.
// Block writes UNNORMALIZED merged O (fp32 planes) + per-(row,head) (m,l);
// attn_merge combines the two halves. VGPR ~112 <= 128 -> 4 blocks/CU.
__global__ __launch_bounds__(256, 4)
void attn_mfma(const unsigned short* __restrict__ wp,
               const unsigned short* __restrict__ wtp,
               float* __restrict__ Op, float* __restrict__ ml, int S) {
    __shared__ unsigned int ShBuf[6336];   // P phase: 4 x 1056 u32; merge: 3 x 2112 f32
    __shared__ float mlbuf[4][64][2];

    int tid = threadIdx.x;
    int wave = tid >> 6, lane = tid & 63;
    int m16 = lane & 15, quad = lane >> 4;
    int zz = blockIdx.x, bb = zz >> 2, hh = zz & 3;
    int q0 = blockIdx.y * 16;
    int kz = blockIdx.z;

    short8 qf[4][2], nqr[2][2];
    {
        size_t qbase = (size_t)(bb * N_ + q0 + m16) * INNER_ + hh * DHEAD_;
#pragma unroll
        for (int p = 0; p < 4; p++)
#pragma unroll
            for (int kc = 0; kc < 2; kc++)
                qf[p][kc] = *(const short8*)(wp + (size_t)p * S + qbase + kc * 32 + quad * 8);
        nqr[0][0] = neg8(qf[0][0]); nqr[0][1] = neg8(qf[0][1]);
        nqr[1][0] = neg8(qf[1][0]); nqr[1][1] = neg8(qf[1][1]);
    }

    float mrow = -1e30f, lrow = 0.f;
    f32x4 Oa[4][2];
#pragma unroll
    for (int ni = 0; ni < 4; ni++) { Oa[ni][0] = (f32x4){0,0,0,0}; Oa[ni][1] = (f32x4){0,0,0,0}; }

    unsigned int* prbu = ShBuf + wave * 1056;

    for (int t = 0; t < 2; t++) {
        int kt = kz * 8 + wave + 4 * t;

        // ---- scores S^T[key][q] (full split precision) ----
        f32x4 sr[4], si[4];
#pragma unroll
        for (int ni = 0; ni < 4; ni++) { sr[ni] = (f32x4){0,0,0,0}; si[ni] = (f32x4){0,0,0,0}; }
#pragma unroll
        for (int ni = 0; ni < 4; ni++) {
            size_t kbase = (size_t)(bb * N_ + kt * 64 + ni * 16 + m16) * INNER_ + hh * DHEAD_;
            short8 kf[4][2];
#pragma unroll
            for (int p = 0; p < 4; p++)
#pragma unroll
                for (int kc = 0; kc < 2; kc++)
                    kf[p][kc] = *(const short8*)(wp + (size_t)p * S + kbase + kc * 32 + quad * 8);
#pragma unroll
            for (int kc = 0; kc < 2; kc++) {
                f32x4 r = sr[ni], im = si[ni];
                r  = mfma16(kf[0][kc], qf[0][kc], r);
                r  = mfma16(kf[0][kc], qf[1][kc], r);
                r  = mfma16(kf[1][kc], qf[0][kc], r);
                r  = mfma16(kf[2][kc], qf[2][kc], r);
                r  = mfma16(kf[2][kc], qf[3][kc], r);
                r  = mfma16(kf[3][kc], qf[2][kc], r);
                im = mfma16(kf[0][kc], qf[2][kc], im);
                im = mfma16(kf[0][kc], qf[3][kc], im);
                im = mfma16(kf[1][kc], qf[2][kc], im);
                im = mfma16(kf[2][kc], nqr[0][kc], im);
                im = mfma16(kf[2][kc], nqr[1][kc], im);
                im = mfma16(kf[3][kc], nqr[0][kc], im);
                sr[ni] = r; si[ni] = im;
            }
        }

        // ---- online softmax on |S| ----
        float mag[4][4], srs[4][4], sis[4][4];
        float mx = -1e30f;
#pragma unroll
        for (int ni = 0; ni < 4; ni++)
#pragma unroll
            for (int r = 0; r < 4; r++) {
                float a = sr[ni][r] * SCALE_, b = si[ni][r] * SCALE_;
                srs[ni][r] = a; sis[ni][r] = b;
                float mg = sqrtf(a * a + b * b);
                mag[ni][r] = mg;
                mx = fmaxf(mx, mg);
            }
        mx = fmaxf(mx, __shfl_xor(mx, 16, 64));
        mx = fmaxf(mx, __shfl_xor(mx, 32, 64));
        float newm = fmaxf(mrow, mx);
        float alpha = __expf(mrow - newm);
        mrow = newm;
        float psum = 0.f;
#pragma unroll
        for (int ni = 0; ni < 4; ni++)
#pragma unroll
            for (int r = 0; r < 4; r++) {
                float p = __expf(mag[ni][r] - newm);
                psum += p;
                float sc = (mag[ni][r] > 0.f) ? (p / mag[ni][r]) : 0.f;
                float pr = (mag[ni][r] > 0.f) ? srs[ni][r] * sc : p;
                float pi = sis[ni][r] * sc;
                int key = ni * 16 + quad * 4 + r;
                prbu[m16 * 66 + key] = ((unsigned)bf16_rne(pi) << 16) | bf16_rne(pr);
            }
        psum += __shfl_xor(psum, 16, 64);
        psum += __shfl_xor(psum, 32, 64);
        lrow = lrow * alpha + psum;
#pragma unroll
        for (int ni = 0; ni < 4; ni++)
#pragma unroll
            for (int r = 0; r < 4; r++) { Oa[ni][0][r] *= alpha; Oa[ni][1][r] *= alpha; }

        // ---- P fragments (hi-only) via per-wave LDS transpose ----
        short8 prh[2], pih[2], nih[2];
#pragma unroll
        for (int kc = 0; kc < 2; kc++) {
            short8 x, y;
#pragma unroll
            for (int j = 0; j < 8; j++) {
                unsigned val = prbu[m16 * 66 + kc * 32 + quad * 8 + j];
                x[j] = (short)(val & 0xffffu);
                y[j] = (short)(val >> 16);
            }
            prh[kc] = x; pih[kc] = y; nih[kc] = neg8(y);
        }

        // ---- O^T += V^T P^T (V hi planes only) ----
#pragma unroll
        for (int ni = 0; ni < 4; ni++) {
            size_t vbase = (size_t)(bb * INNER_ + hh * DHEAD_ + ni * 16 + m16) * N_ + kt * 64;
            short8 vr0 = *(const short8*)(wtp + 0 * (size_t)S + vbase + quad * 8);
            short8 vr1 = *(const short8*)(wtp + 0 * (size_t)S + vbase + 32 + quad * 8);
            short8 vi0 = *(const short8*)(wtp + 2 * (size_t)S + vbase + quad * 8);
            short8 vi1 = *(const short8*)(wtp + 2 * (size_t)S + vbase + 32 + quad * 8);
            f32x4 orv = Oa[ni][0], oiv = Oa[ni][1];
            orv = mfma16(vr0, prh[0], orv);
            orv = mfma16(vi0, nih[0], orv);
            orv = mfma16(vr1, prh[1], orv);
            orv = mfma16(vi1, nih[1], orv);
            oiv = mfma16(vr0, pih[0], oiv);
            oiv = mfma16(vi0, prh[0], oiv);
            oiv = mfma16(vr1, pih[1], oiv);
            oiv = mfma16(vi1, prh[1], oiv);
            Oa[ni][0] = orv; Oa[ni][1] = oiv;
        }
    }

    // ---- intra-block 4-way merge; write UNNORMALIZED O + per-(row,head) (m,l) ----
    float* Obuf = (float*)ShBuf;
    __syncthreads();
    if (wave != 0) {
        float* mb = Obuf + (wave - 1) * 2112 + lane * 33;
#pragma unroll
        for (int ni = 0; ni < 4; ni++)
#pragma unroll
            for (int r = 0; r < 4; r++) {
                mb[ni * 8 + r]     = Oa[ni][0][r];
                mb[ni * 8 + 4 + r] = Oa[ni][1][r];
            }
        mlbuf[wave][lane][0] = mrow;
        mlbuf[wave][lane][1] = lrow;
    }
    __syncthreads();
    if (wave == 0) {
        float mm = mrow;
#pragma unroll
        for (int w = 1; w < 4; w++) mm = fmaxf(mm, mlbuf[w][lane][0]);
        float a0 = __expf(mrow - mm);
        float ltot = a0 * lrow;
        float aw[3];
#pragma unroll
        for (int w = 1; w < 4; w++) {
            aw[w - 1] = __expf(mlbuf[w][lane][0] - mm);
            ltot += aw[w - 1] * mlbuf[w][lane][1];
        }
        size_t obase = (size_t)(bb * N_ + q0 + m16) * INNER_ + hh * DHEAD_;
        float* opr = Op + (size_t)kz * 2 * S;
        float* opi = opr + S;
#pragma unroll
        for (int ni = 0; ni < 4; ni++)
#pragma unroll
            for (int r = 0; r < 4; r++) {
                float vr = a0 * Oa[ni][0][r];
                float vi = a0 * Oa[ni][1][r];
#pragma unroll
                for (int w = 1; w < 4; w++) {
                    vr += aw[w - 1] * Obuf[(w - 1) * 2112 + lane * 33 + ni * 8 + r];
                    vi += aw[w - 1] * Obuf[(w - 1) * 2112 + lane * 33 + ni * 8 + 4 + r];
                }
                size_t o = obase + ni * 16 + quad * 4 + r;
                opr[o] = vr;
                opi[o] = vi;
            }
        if (quad == 0) {
            int row = bb * N_ + q0 + m16;
            // per-(row, head) slot: row*4 + hh  (round-11 bug: head index was dropped)
            ((float2*)ml)[kz * 8192 + row * 4 + hh] = make_float2(mm, ltot);
        }
    }
}

// ---------------- merge the two key-halves, emit 4 bf16 planes ----------------
__global__ void attn_merge(const float* __restrict__ Op, const float* __restrict__ ml,
                           unsigned short* __restrict__ aop, int S) {
    int idx = blockIdx.x * 256 + threadIdx.x;
    int row = idx >> 8;                          // (bb*N + n), INNER = 256
    int hh = (idx >> 6) & 3;                     // head from column block
    float2 ml0 = ((const float2*)ml)[row * 4 + hh];
    float2 ml1 = ((const float2*)ml)[8192 + row * 4 + hh];
    float mm = fmaxf(ml0.x, ml1.x);
    float a0 = __expf(ml0.x - mm), a1 = __expf(ml1.x - mm);
    float invl = 1.f / (a0 * ml0.y + a1 * ml1.y);
    float vr = (a0 * Op[idx] + a1 * Op[2 * (size_t)S + idx]) * invl;
    float vi = (a0 * Op[(size_t)S + idx] + a1 * Op[3 * (size_t)S + idx]) * invl;
    unsigned short h0, h1, h2, h3;
    split2(vr, h0, h1);
    split2(vi, h2, h3);
    aop[0 * (size_t)S + idx] = h0;
    aop[1 * (size_t)S + idx] = h1;
    aop[2 * (size_t)S + idx] = h2;
    aop[3 * (size_t)S + idx] = h3;
}

// ---------------- output pack (fallback only) ----------------
__global__ void pack_real(const float* __restrict__ xr, float* __restrict__ out, int cap) {
    int idx = blockIdx.x * 256 + threadIdx.x;
    if (idx < cap) out[idx] = xr[idx];
}

// ---------------- host orchestration ----------------
extern "C" void kernel_launch(void* const* d_in, const int* in_sizes, int n_in,
                              void* d_out, int out_size, void* d_ws, size_t ws_size,
                              hipStream_t stream) {
    const float* in_xre = (const float*)d_in[0];
    const float* in_xim = (const float*)d_in[1];
    const float* ln1wr = (const float*)d_in[2];
    const float* ln1wi = (const float*)d_in[3];
    const float* ln1br = (const float*)d_in[4];
    const float* ln1bi = (const float*)d_in[5];
    const float* qkvr  = (const float*)d_in[6];
    const float* qkvi  = (const float*)d_in[7];
    const float* outwr = (const float*)d_in[8];
    const float* outwi = (const float*)d_in[9];
    const float* outbr = (const float*)d_in[10];
    const float* outbi = (const float*)d_in[11];
    const float* ln2wr = (const float*)d_in[12];
    const float* ln2wi = (const float*)d_in[13];
    const float* ln2br = (const float*)d_in[14];
    const float* ln2bi = (const float*)d_in[15];
    const float* ffr   = (const float*)d_in[16];
    const float* ffi   = (const float*)d_in[17];

    const size_t S = (size_t)B_ * N_ * DIM_;          // 524288
    const int    Si = (int)S;

    float* ws  = (float*)d_ws;
    float* xre = ws;            float* xim = xre + S;
    float* xnr = xim + S;       float* xni = xnr + S;
    float* Opart = xni + S;                              // 4*S fp32 (2 halves x re/im)
    float* mlb   = Opart + 4 * S;                        // 2*8192 float2 = 32768 floats

    unsigned short* xnp   = (unsigned short*)(mlb + 32768);
    unsigned short* aop   = xnp + 4 * S;
    unsigned short* wpb   = aop + 4 * S;
    unsigned short* wtpb  = wpb + 4 * S;
    unsigned short* qkvp  = wtpb + 4 * S;
    unsigned short* outwp = qkvp + (size_t)DEPTH_ * 4 * 65536;
    unsigned short* ffp   = outwp + (size_t)DEPTH_ * 4 * 65536;

    wsplit_all<<<3 * DEPTH_ * 65536 / 256, 256, 0, stream>>>(
        qkvr, qkvi, outwr, outwi, ffr, ffi, qkvp, outwp, ffp);

    const int MR = B_ * N_;
    dim3 gGemm(MR / 16, INNER_ / 16);       // (128, 16): x = M-tile -> XCD-local A
    dim3 gAttn(B_ * HEADS_, N_ / 16, 2);    // (8, 64, 2): x = (b,h) -> XCD-local K/V
    int eBlocks = (int)(S / 256);

    bool directOut = (out_size >= (int)(2 * S));
    float* foutR = directOut ? (float*)d_out : xre;
    float* foutI = directOut ? (float*)d_out + S : xim;

    for (int l = 0; l < DEPTH_; l++) {
        const float* xinR = (l == 0) ? in_xre : xre;
        const float* xinI = (l == 0) ? in_xim : xim;

        ln_kernel<<<MR, 64, 0, stream>>>(xinR, xinI,
            ln1wr + l * DIM_, ln1wi + l * DIM_, ln1br + l * DIM_, ln1bi + l * DIM_,
            xnr, xni, xnp, Si);

        gemm_mfma<1><<<gGemm, 64, 0, stream>>>(xnp, Si, qkvp + (size_t)l * 4 * 65536,
            wpb, wtpb, nullptr, nullptr, nullptr, nullptr, nullptr, nullptr, Si);

        attn_mfma<<<gAttn, 256, 0, stream>>>(wpb, wtpb, Opart, mlb, Si);
        attn_merge<<<eBlocks, 256, 0, stream>>>(Opart, mlb, aop, Si);

        gemm_mfma<2><<<gGemm, 64, 0, stream>>>(aop, Si, outwp + (size_t)l * 4 * 65536,
            nullptr, nullptr, outbr + l * DIM_, outbi + l * DIM_, xinR, xinI, xre, xim, Si);

        ln_kernel<<<MR, 64, 0, stream>>>(xre, xim,
            ln2wr + l * DIM_, ln2wi + l * DIM_, ln2br + l * DIM_, ln2bi + l * DIM_,
            xnr, xni, xnp, Si);

        float* oR = (l == DEPTH_ - 1) ? foutR : xre;
        float* oI = (l == DEPTH_ - 1) ? foutI : xim;
        gemm_mfma<3><<<gGemm, 64, 0, stream>>>(xnp, Si, ffp + (size_t)l * 4 * 65536,
            nullptr, nullptr, nullptr, nullptr, xnr, xni, oR, oI, Si);
    }

    if (!directOut) {
        pack_real<<<eBlocks, 256, 0, stream>>>(xre, (float*)d_out, out_size);
    }
}

// Round 13
// 591.581 us; speedup vs baseline: 1.1344x; 1.1344x over previous
//
#include <hip/hip_runtime.h>
#include <math.h>

#define B_ 2
#define N_ 1024
#define DIM_ 256
#define DEPTH_ 4
#define HEADS_ 4
#define DHEAD_ 64
#define INNER_ 256
#define SCALE_ 0.125f
#define STEP_ 0.1f
#define LAMBD_ 0.1f
#define EPS_ 1e-5f

typedef __attribute__((ext_vector_type(8))) short short8;
typedef __attribute__((ext_vector_type(4))) float f32x4;

// ---------------- bf16 split helpers ----------------
__device__ __forceinline__ unsigned short bf16_rne(float x) {
    unsigned u = __float_as_uint(x);
    unsigned r = (u + 0x7FFFu + ((u >> 16) & 1u)) >> 16;
    return (unsigned short)r;
}
__device__ __forceinline__ float bf16_tof(unsigned short h) {
    return __uint_as_float(((unsigned)h) << 16);
}
__device__ __forceinline__ void split2(float x, unsigned short& hi, unsigned short& lo) {
    hi = bf16_rne(x);
    lo = bf16_rne(x - bf16_tof(hi));
}
__device__ __forceinline__ f32x4 mfma16(short8 a, short8 b, f32x4 c) {
    return __builtin_amdgcn_mfma_f32_16x16x32_bf16(a, b, c, 0, 0, 0);
}
__device__ __forceinline__ short8 neg8(short8 v) {
    union { short8 s; unsigned u[4]; } a; a.s = v;
    a.u[0] ^= 0x80008000u; a.u[1] ^= 0x80008000u;
    a.u[2] ^= 0x80008000u; a.u[3] ^= 0x80008000u;
    return a.s;
}

// ---------------- complex layernorm: one wave per row, shfl-only reductions ----------------
__global__ __launch_bounds__(64)
void ln_kernel(const float* __restrict__ xr, const float* __restrict__ xi,
               const float* __restrict__ wr, const float* __restrict__ wi,
               const float* __restrict__ br, const float* __restrict__ bi,
               float* __restrict__ outr, float* __restrict__ outi,
               unsigned short* __restrict__ planes, int S) {
    int row = blockIdx.x;
    int lane = threadIdx.x;
    int base = row * DIM_ + lane * 4;

    float4 xr4 = *(const float4*)(xr + base);
    float4 xi4 = *(const float4*)(xi + base);
    float ar[4] = {xr4.x, xr4.y, xr4.z, xr4.w};
    float ai[4] = {xi4.x, xi4.y, xi4.z, xi4.w};

    float sr = ar[0] + ar[1] + ar[2] + ar[3];
    float si = ai[0] + ai[1] + ai[2] + ai[3];
#pragma unroll
    for (int o = 1; o < 64; o <<= 1) {
        sr += __shfl_xor(sr, o, 64);
        si += __shfl_xor(si, o, 64);
    }
    float mre = sr * (1.f / DIM_), mim = si * (1.f / DIM_);

    float drv[4], div[4];
    float vr = 0.f, vi = 0.f;
#pragma unroll
    for (int j = 0; j < 4; j++) {
        drv[j] = ar[j] - mre;
        div[j] = ai[j] - mim;
        vr += drv[j] * drv[j];
        vi += div[j] * div[j];
    }
#pragma unroll
    for (int o = 1; o < 64; o <<= 1) {
        vr += __shfl_xor(vr, o, 64);
        vi += __shfl_xor(vi, o, 64);
    }
    float c = vr * (1.f / DIM_) + EPS_;
    float d = vi * (1.f / DIM_);
    float r = sqrtf(c * c + d * d);
    float sre = sqrtf(0.5f * (r + c));
    float sim = sqrtf(fmaxf(0.5f * (r - c), 0.f));
    float inv = 1.f / r;

    int wc = lane * 4;
    float4 wr4 = *(const float4*)(wr + wc);
    float4 wi4 = *(const float4*)(wi + wc);
    float4 br4 = *(const float4*)(br + wc);
    float4 bi4 = *(const float4*)(bi + wc);
    float wrv[4] = {wr4.x, wr4.y, wr4.z, wr4.w};
    float wiv[4] = {wi4.x, wi4.y, wi4.z, wi4.w};
    float brv[4] = {br4.x, br4.y, br4.z, br4.w};
    float biv[4] = {bi4.x, bi4.y, bi4.z, bi4.w};

    float orr[4], oii[4];
    unsigned short rh[4], rl[4], ih[4], il[4];
#pragma unroll
    for (int j = 0; j < 4; j++) {
        float nr = (drv[j] * sre + div[j] * sim) * inv;
        float ni = (div[j] * sre - drv[j] * sim) * inv;
        orr[j] = wrv[j] * nr - wiv[j] * ni + brv[j];
        oii[j] = wrv[j] * ni + wiv[j] * nr + biv[j];
        split2(orr[j], rh[j], rl[j]);
        split2(oii[j], ih[j], il[j]);
    }
    *(float4*)(outr + base) = make_float4(orr[0], orr[1], orr[2], orr[3]);
    *(float4*)(outi + base) = make_float4(oii[0], oii[1], oii[2], oii[3]);
    *(ushort4*)(planes + 0 * (size_t)S + base) = make_ushort4(rh[0], rh[1], rh[2], rh[3]);
    *(ushort4*)(planes + 1 * (size_t)S + base) = make_ushort4(rl[0], rl[1], rl[2], rl[3]);
    *(ushort4*)(planes + 2 * (size_t)S + base) = make_ushort4(ih[0], ih[1], ih[2], ih[3]);
    *(ushort4*)(planes + 3 * (size_t)S + base) = make_ushort4(il[0], il[1], il[2], il[3]);
}

// ---------------- fused weight split (qkv + outw + ff in one dispatch) ----------------
__global__ void wsplit_all(const float* __restrict__ s0r, const float* __restrict__ s0i,
                           const float* __restrict__ s1r, const float* __restrict__ s1i,
                           const float* __restrict__ s2r, const float* __restrict__ s2i,
                           unsigned short* __restrict__ d0,
                           unsigned short* __restrict__ d1,
                           unsigned short* __restrict__ d2) {
    const int PER = DEPTH_ * 65536;
    int gid = blockIdx.x * 256 + threadIdx.x;
    int sel = gid / PER;
    int idx = gid - sel * PER;
    const float* wr = (sel == 0) ? s0r : (sel == 1) ? s1r : s2r;
    const float* wi = (sel == 0) ? s0i : (sel == 1) ? s1i : s2i;
    unsigned short* dst = (sel == 0) ? d0 : (sel == 1) ? d1 : d2;
    int l = idx >> 16, e = idx & 65535;
    unsigned short rh, rl, ih, il;
    split2(wr[idx], rh, rl);
    split2(wi[idx], ih, il);
    size_t base = (size_t)l * 4 * 65536;
    dst[base + 0 * 65536 + e] = rh;
    dst[base + 1 * 65536 + e] = rl;
    dst[base + 2 * 65536 + e] = ih;
    dst[base + 3 * 65536 + e] = il;
}

// ---------------- MFMA complex GEMM (unchanged) ----------------
template <int MODE>
__global__ __launch_bounds__(64)
void gemm_mfma(const unsigned short* __restrict__ Ap, int aStride,
               const unsigned short* __restrict__ Bp,
               unsigned short* __restrict__ wpo, unsigned short* __restrict__ wtpo,
               const float* __restrict__ biasR, const float* __restrict__ biasI,
               const float* resR, const float* resI,
               float* xoR, float* xoI, int S) {
    const int K = 256;
    int tileM = blockIdx.x * 16, tileN = blockIdx.y * 16;
    int lane = threadIdx.x;
    int m16 = lane & 15, quad = lane >> 4;

    f32x4 accP = (f32x4){0,0,0,0}, accN = (f32x4){0,0,0,0};
    f32x4 accIa = (f32x4){0,0,0,0}, accIb = (f32x4){0,0,0,0};

#pragma unroll
    for (int k0 = 0; k0 < 256; k0 += 32) {
        int kb = k0 + quad * 8;
        short8 a[4], b[4];
#pragma unroll
        for (int p = 0; p < 4; p++) {
            a[p] = *(const short8*)(Ap + (size_t)p * aStride + (size_t)(tileM + m16) * K + kb);
            b[p] = *(const short8*)(Bp + (size_t)p * 65536  + (size_t)(tileN + m16) * K + kb);
        }
        accP  = mfma16(a[0], b[0], accP);
        accP  = mfma16(a[0], b[1], accP);
        accP  = mfma16(a[1], b[0], accP);
        accN  = mfma16(a[2], b[2], accN);
        accN  = mfma16(a[2], b[3], accN);
        accN  = mfma16(a[3], b[2], accN);
        accIa = mfma16(a[0], b[2], accIa);
        accIa = mfma16(a[0], b[3], accIa);
        accIa = mfma16(a[1], b[2], accIa);
        accIb = mfma16(a[2], b[0], accIb);
        accIb = mfma16(a[2], b[1], accIb);
        accIb = mfma16(a[3], b[0], accIb);
    }

#pragma unroll
    for (int r = 0; r < 4; r++) {
        int row = tileM + quad * 4 + r;
        int col = tileN + m16;
        size_t g = (size_t)row * 256 + col;
        float vr = accP[r] - accN[r];
        float vi = accIa[r] + accIb[r];
        if (MODE == 1) {
            unsigned short h0, h1, h2, h3;
            split2(vr, h0, h1);
            split2(vi, h2, h3);
            size_t tidx = ((size_t)(row >> 10) * 256 + col) * 1024 + (row & 1023);
            wpo[0 * (size_t)S + g] = h0;
            wpo[1 * (size_t)S + g] = h1;
            wpo[2 * (size_t)S + g] = h2;
            wpo[3 * (size_t)S + g] = h3;
            wtpo[0 * (size_t)S + tidx] = h0;
            wtpo[1 * (size_t)S + tidx] = h1;
            wtpo[2 * (size_t)S + tidx] = h2;
            wtpo[3 * (size_t)S + tidx] = h3;
        } else if (MODE == 2) {
            xoR[g] = vr + biasR[col] + resR[g];
            xoI[g] = vi + biasI[col] + resI[g];
        } else {
            float zr = resR[g] + STEP_ * vr - STEP_ * LAMBD_;
            float zi = resI[g] + STEP_ * vi;
            xoR[g] = fmaxf(zr, 0.f);
            xoI[g] = fmaxf(zi, 0.f);
        }
    }
}

// ---------------- MFMA flash attention: split-K across blocks, low-VGPR ----------------
// grid (B*H, N/16, 2), 256 threads, __launch_bounds__(256,2) (floor decl — do NOT
// raise to 4: unified VGPR+AGPR cap 128 causes scratch spill, r9/r12 evidence).
// nqr registers eliminated: Ki*(-Qr) computed as (-Ki)*Qr with transient negated K.
// Block writes UNNORMALIZED merged O + per-(row,head) (m,l); attn_merge combines.
__global__ __launch_bounds__(256, 2)
void attn_mfma(const unsigned short* __restrict__ wp,
               const unsigned short* __restrict__ wtp,
               float* __restrict__ Op, float* __restrict__ ml, int S) {
    __shared__ unsigned int ShBuf[6336];   // P phase: 4 x 1056 u32; merge: 3 x 2112 f32
    __shared__ float mlbuf[4][64][2];

    int tid = threadIdx.x;
    int wave = tid >> 6, lane = tid & 63;
    int m16 = lane & 15, quad = lane >> 4;
    int zz = blockIdx.x, bb = zz >> 2, hh = zz & 3;
    int q0 = blockIdx.y * 16;
    int kz = blockIdx.z;

    short8 qf[4][2];
    {
        size_t qbase = (size_t)(bb * N_ + q0 + m16) * INNER_ + hh * DHEAD_;
#pragma unroll
        for (int p = 0; p < 4; p++)
#pragma unroll
            for (int kc = 0; kc < 2; kc++)
                qf[p][kc] = *(const short8*)(wp + (size_t)p * S + qbase + kc * 32 + quad * 8);
    }

    float mrow = -1e30f, lrow = 0.f;
    f32x4 Oa[4][2];
#pragma unroll
    for (int ni = 0; ni < 4; ni++) { Oa[ni][0] = (f32x4){0,0,0,0}; Oa[ni][1] = (f32x4){0,0,0,0}; }

    unsigned int* prbu = ShBuf + wave * 1056;

    for (int t = 0; t < 2; t++) {
        int kt = kz * 8 + wave + 4 * t;

        // ---- scores S^T[key][q] (full split precision) ----
        f32x4 sr[4], si[4];
#pragma unroll
        for (int ni = 0; ni < 4; ni++) { sr[ni] = (f32x4){0,0,0,0}; si[ni] = (f32x4){0,0,0,0}; }
#pragma unroll
        for (int ni = 0; ni < 4; ni++) {
            size_t kbase = (size_t)(bb * N_ + kt * 64 + ni * 16 + m16) * INNER_ + hh * DHEAD_;
            short8 kf[4][2];
#pragma unroll
            for (int p = 0; p < 4; p++)
#pragma unroll
                for (int kc = 0; kc < 2; kc++)
                    kf[p][kc] = *(const short8*)(wp + (size_t)p * S + kbase + kc * 32 + quad * 8);
#pragma unroll
            for (int kc = 0; kc < 2; kc++) {
                short8 nki_h = neg8(kf[2][kc]);      // transient: (-Ki_hi)
                short8 nki_l = neg8(kf[3][kc]);      // transient: (-Ki_lo)
                f32x4 r = sr[ni], im = si[ni];
                r  = mfma16(kf[0][kc], qf[0][kc], r);
                r  = mfma16(kf[0][kc], qf[1][kc], r);
                r  = mfma16(kf[1][kc], qf[0][kc], r);
                r  = mfma16(kf[2][kc], qf[2][kc], r);
                r  = mfma16(kf[2][kc], qf[3][kc], r);
                r  = mfma16(kf[3][kc], qf[2][kc], r);
                im = mfma16(kf[0][kc], qf[2][kc], im);
                im = mfma16(kf[0][kc], qf[3][kc], im);
                im = mfma16(kf[1][kc], qf[2][kc], im);
                im = mfma16(nki_h, qf[0][kc], im);   // (-Ki)*Qr == Ki*(-Qr)
                im = mfma16(nki_h, qf[1][kc], im);
                im = mfma16(nki_l, qf[0][kc], im);
                sr[ni] = r; si[ni] = im;
            }
        }

        // ---- online softmax on |S| ----
        float mag[4][4], srs[4][4], sis[4][4];
        float mx = -1e30f;
#pragma unroll
        for (int ni = 0; ni < 4; ni++)
#pragma unroll
            for (int r = 0; r < 4; r++) {
                float a = sr[ni][r] * SCALE_, b = si[ni][r] * SCALE_;
                srs[ni][r] = a; sis[ni][r] = b;
                float mg = sqrtf(a * a + b * b);
                mag[ni][r] = mg;
                mx = fmaxf(mx, mg);
            }
        mx = fmaxf(mx, __shfl_xor(mx, 16, 64));
        mx = fmaxf(mx, __shfl_xor(mx, 32, 64));
        float newm = fmaxf(mrow, mx);
        float alpha = __expf(mrow - newm);
        mrow = newm;
        float psum = 0.f;
#pragma unroll
        for (int ni = 0; ni < 4; ni++)
#pragma unroll
            for (int r = 0; r < 4; r++) {
                float p = __expf(mag[ni][r] - newm);
                psum += p;
                float sc = (mag[ni][r] > 0.f) ? (p / mag[ni][r]) : 0.f;
                float pr = (mag[ni][r] > 0.f) ? srs[ni][r] * sc : p;
                float pi = sis[ni][r] * sc;
                int key = ni * 16 + quad * 4 + r;
                prbu[m16 * 66 + key] = ((unsigned)bf16_rne(pi) << 16) | bf16_rne(pr);
            }
        psum += __shfl_xor(psum, 16, 64);
        psum += __shfl_xor(psum, 32, 64);
        lrow = lrow * alpha + psum;
#pragma unroll
        for (int ni = 0; ni < 4; ni++)
#pragma unroll
            for (int r = 0; r < 4; r++) { Oa[ni][0][r] *= alpha; Oa[ni][1][r] *= alpha; }

        // ---- P fragments (hi-only) via per-wave LDS transpose ----
        short8 prh[2], pih[2], nih[2];
#pragma unroll
        for (int kc = 0; kc < 2; kc++) {
            short8 x, y;
#pragma unroll
            for (int j = 0; j < 8; j++) {
                unsigned val = prbu[m16 * 66 + kc * 32 + quad * 8 + j];
                x[j] = (short)(val & 0xffffu);
                y[j] = (short)(val >> 16);
            }
            prh[kc] = x; pih[kc] = y; nih[kc] = neg8(y);
        }

        // ---- O^T += V^T P^T (V hi planes only) ----
#pragma unroll
        for (int ni = 0; ni < 4; ni++) {
            size_t vbase = (size_t)(bb * INNER_ + hh * DHEAD_ + ni * 16 + m16) * N_ + kt * 64;
            short8 vr0 = *(const short8*)(wtp + 0 * (size_t)S + vbase + quad * 8);
            short8 vr1 = *(const short8*)(wtp + 0 * (size_t)S + vbase + 32 + quad * 8);
            short8 vi0 = *(const short8*)(wtp + 2 * (size_t)S + vbase + quad * 8);
            short8 vi1 = *(const short8*)(wtp + 2 * (size_t)S + vbase + 32 + quad * 8);
            f32x4 orv = Oa[ni][0], oiv = Oa[ni][1];
            orv = mfma16(vr0, prh[0], orv);
            orv = mfma16(vi0, nih[0], orv);
            orv = mfma16(vr1, prh[1], orv);
            orv = mfma16(vi1, nih[1], orv);
            oiv = mfma16(vr0, pih[0], oiv);
            oiv = mfma16(vi0, prh[0], oiv);
            oiv = mfma16(vr1, pih[1], oiv);
            oiv = mfma16(vi1, prh[1], oiv);
            Oa[ni][0] = orv; Oa[ni][1] = oiv;
        }
    }

    // ---- intra-block 4-way merge; write UNNORMALIZED O + per-(row,head) (m,l) ----
    float* Obuf = (float*)ShBuf;
    __syncthreads();
    if (wave != 0) {
        float* mb = Obuf + (wave - 1) * 2112 + lane * 33;
#pragma unroll
        for (int ni = 0; ni < 4; ni++)
#pragma unroll
            for (int r = 0; r < 4; r++) {
                mb[ni * 8 + r]     = Oa[ni][0][r];
                mb[ni * 8 + 4 + r] = Oa[ni][1][r];
            }
        mlbuf[wave][lane][0] = mrow;
        mlbuf[wave][lane][1] = lrow;
    }
    __syncthreads();
    if (wave == 0) {
        float mm = mrow;
#pragma unroll
        for (int w = 1; w < 4; w++) mm = fmaxf(mm, mlbuf[w][lane][0]);
        float a0 = __expf(mrow - mm);
        float ltot = a0 * lrow;
        float aw[3];
#pragma unroll
        for (int w = 1; w < 4; w++) {
            aw[w - 1] = __expf(mlbuf[w][lane][0] - mm);
            ltot += aw[w - 1] * mlbuf[w][lane][1];
        }
        size_t obase = (size_t)(bb * N_ + q0 + m16) * INNER_ + hh * DHEAD_;
        float* opr = Op + (size_t)kz * 2 * S;
        float* opi = opr + S;
#pragma unroll
        for (int ni = 0; ni < 4; ni++)
#pragma unroll
            for (int r = 0; r < 4; r++) {
                float vr = a0 * Oa[ni][0][r];
                float vi = a0 * Oa[ni][1][r];
#pragma unroll
                for (int w = 1; w < 4; w++) {
                    vr += aw[w - 1] * Obuf[(w - 1) * 2112 + lane * 33 + ni * 8 + r];
                    vi += aw[w - 1] * Obuf[(w - 1) * 2112 + lane * 33 + ni * 8 + 4 + r];
                }
                size_t o = obase + ni * 16 + quad * 4 + r;
                opr[o] = vr;
                opi[o] = vi;
            }
        if (quad == 0) {
            int row = bb * N_ + q0 + m16;
            ((float2*)ml)[kz * 8192 + row * 4 + hh] = make_float2(mm, ltot);
        }
    }
}

// ---------------- merge the two key-halves, emit 4 bf16 planes ----------------
__global__ void attn_merge(const float* __restrict__ Op, const float* __restrict__ ml,
                           unsigned short* __restrict__ aop, int S) {
    int idx = blockIdx.x * 256 + threadIdx.x;
    int row = idx >> 8;
    int hh = (idx >> 6) & 3;
    float2 ml0 = ((const float2*)ml)[row * 4 + hh];
    float2 ml1 = ((const float2*)ml)[8192 + row * 4 + hh];
    float mm = fmaxf(ml0.x, ml1.x);
    float a0 = __expf(ml0.x - mm), a1 = __expf(ml1.x - mm);
    float invl = 1.f / (a0 * ml0.y + a1 * ml1.y);
    float vr = (a0 * Op[idx] + a1 * Op[2 * (size_t)S + idx]) * invl;
    float vi = (a0 * Op[(size_t)S + idx] + a1 * Op[3 * (size_t)S + idx]) * invl;
    unsigned short h0, h1, h2, h3;
    split2(vr, h0, h1);
    split2(vi, h2, h3);
    aop[0 * (size_t)S + idx] = h0;
    aop[1 * (size_t)S + idx] = h1;
    aop[2 * (size_t)S + idx] = h2;
    aop[3 * (size_t)S + idx] = h3;
}

// ---------------- output pack (fallback only) ----------------
__global__ void pack_real(const float* __restrict__ xr, float* __restrict__ out, int cap) {
    int idx = blockIdx.x * 256 + threadIdx.x;
    if (idx < cap) out[idx] = xr[idx];
}

// ---------------- host orchestration ----------------
extern "C" void kernel_launch(void* const* d_in, const int* in_sizes, int n_in,
                              void* d_out, int out_size, void* d_ws, size_t ws_size,
                              hipStream_t stream) {
    const float* in_xre = (const float*)d_in[0];
    const float* in_xim = (const float*)d_in[1];
    const float* ln1wr = (const float*)d_in[2];
    const float* ln1wi = (const float*)d_in[3];
    const float* ln1br = (const float*)d_in[4];
    const float* ln1bi = (const float*)d_in[5];
    const float* qkvr  = (const float*)d_in[6];
    const float* qkvi  = (const float*)d_in[7];
    const float* outwr = (const float*)d_in[8];
    const float* outwi = (const float*)d_in[9];
    const float* outbr = (const float*)d_in[10];
    const float* outbi = (const float*)d_in[11];
    const float* ln2wr = (const float*)d_in[12];
    const float* ln2wi = (const float*)d_in[13];
    const float* ln2br = (const float*)d_in[14];
    const float* ln2bi = (const float*)d_in[15];
    const float* ffr   = (const float*)d_in[16];
    const float* ffi   = (const float*)d_in[17];

    const size_t S = (size_t)B_ * N_ * DIM_;          // 524288
    const int    Si = (int)S;

    float* ws  = (float*)d_ws;
    float* xre = ws;            float* xim = xre + S;
    float* xnr = xim + S;       float* xni = xnr + S;
    float* Opart = xni + S;                              // 4*S fp32 (2 halves x re/im)
    float* mlb   = Opart + 4 * S;                        // 2*8192 float2 = 32768 floats

    unsigned short* xnp   = (unsigned short*)(mlb + 32768);
    unsigned short* aop   = xnp + 4 * S;
    unsigned short* wpb   = aop + 4 * S;
    unsigned short* wtpb  = wpb + 4 * S;
    unsigned short* qkvp  = wtpb + 4 * S;
    unsigned short* outwp = qkvp + (size_t)DEPTH_ * 4 * 65536;
    unsigned short* ffp   = outwp + (size_t)DEPTH_ * 4 * 65536;

    wsplit_all<<<3 * DEPTH_ * 65536 / 256, 256, 0, stream>>>(
        qkvr, qkvi, outwr, outwi, ffr, ffi, qkvp, outwp, ffp);

    const int MR = B_ * N_;
    dim3 gGemm(MR / 16, INNER_ / 16);       // (128, 16): x = M-tile -> XCD-local A
    dim3 gAttn(B_ * HEADS_, N_ / 16, 2);    // (8, 64, 2): x = (b,h) -> XCD-local K/V
    int eBlocks = (int)(S / 256);

    bool directOut = (out_size >= (int)(2 * S));
    float* foutR = directOut ? (float*)d_out : xre;
    float* foutI = directOut ? (float*)d_out + S : xim;

    for (int l = 0; l < DEPTH_; l++) {
        const float* xinR = (l == 0) ? in_xre : xre;
        const float* xinI = (l == 0) ? in_xim : xim;

        ln_kernel<<<MR, 64, 0, stream>>>(xinR, xinI,
            ln1wr + l * DIM_, ln1wi + l * DIM_, ln1br + l * DIM_, ln1bi + l * DIM_,
            xnr, xni, xnp, Si);

        gemm_mfma<1><<<gGemm, 64, 0, stream>>>(xnp, Si, qkvp + (size_t)l * 4 * 65536,
            wpb, wtpb, nullptr, nullptr, nullptr, nullptr, nullptr, nullptr, Si);

        attn_mfma<<<gAttn, 256, 0, stream>>>(wpb, wtpb, Opart, mlb, Si);
        attn_merge<<<eBlocks, 256, 0, stream>>>(Opart, mlb, aop, Si);

        gemm_mfma<2><<<gGemm, 64, 0, stream>>>(aop, Si, outwp + (size_t)l * 4 * 65536,
            nullptr, nullptr, outbr + l * DIM_, outbi + l * DIM_, xinR, xinI, xre, xim, Si);

        ln_kernel<<<MR, 64, 0, stream>>>(xre, xim,
            ln2wr + l * DIM_, ln2wi + l * DIM_, ln2br + l * DIM_, ln2bi + l * DIM_,
            xnr, xni, xnp, Si);

        float* oR = (l == DEPTH_ - 1) ? foutR : xre;
        float* oI = (l == DEPTH_ - 1) ? foutI : xim;
        gemm_mfma<3><<<gGemm, 64, 0, stream>>>(xnp, Si, ffp + (size_t)l * 4 * 65536,
            nullptr, nullptr, nullptr, nullptr, xnr, xni, oR, oI, Si);
    }

    if (!directOut) {
        pack_real<<<eBlocks, 256, 0, stream>>>(xre, (float*)d_out, out_size);
    }
}

// Round 14
// 526.352 us; speedup vs baseline: 1.2750x; 1.1239x over previous
//
#include <hip/hip_runtime.h>
#include <math.h>

#define B_ 2
#define N_ 1024
#define DIM_ 256
#define DEPTH_ 4
#define HEADS_ 4
#define DHEAD_ 64
#define INNER_ 256
#define SCALE_ 0.125f
#define STEP_ 0.1f
#define LAMBD_ 0.1f
#define EPS_ 1e-5f

typedef __attribute__((ext_vector_type(8))) short short8;
typedef __attribute__((ext_vector_type(4))) float f32x4;

// ---------------- bf16 split helpers ----------------
__device__ __forceinline__ unsigned short bf16_rne(float x) {
    unsigned u = __float_as_uint(x);
    unsigned r = (u + 0x7FFFu + ((u >> 16) & 1u)) >> 16;
    return (unsigned short)r;
}
__device__ __forceinline__ float bf16_tof(unsigned short h) {
    return __uint_as_float(((unsigned)h) << 16);
}
__device__ __forceinline__ void split2(float x, unsigned short& hi, unsigned short& lo) {
    hi = bf16_rne(x);
    lo = bf16_rne(x - bf16_tof(hi));
}
__device__ __forceinline__ f32x4 mfma16(short8 a, short8 b, f32x4 c) {
    return __builtin_amdgcn_mfma_f32_16x16x32_bf16(a, b, c, 0, 0, 0);
}
__device__ __forceinline__ short8 neg8(short8 v) {
    union { short8 s; unsigned u[4]; } a; a.s = v;
    a.u[0] ^= 0x80008000u; a.u[1] ^= 0x80008000u;
    a.u[2] ^= 0x80008000u; a.u[3] ^= 0x80008000u;
    return a.s;
}

// ---------------- complex layernorm: one wave per row, shfl-only reductions ----------------
__global__ __launch_bounds__(64)
void ln_kernel(const float* __restrict__ xr, const float* __restrict__ xi,
               const float* __restrict__ wr, const float* __restrict__ wi,
               const float* __restrict__ br, const float* __restrict__ bi,
               float* __restrict__ outr, float* __restrict__ outi,
               unsigned short* __restrict__ planes, int S) {
    int row = blockIdx.x;
    int lane = threadIdx.x;
    int base = row * DIM_ + lane * 4;

    float4 xr4 = *(const float4*)(xr + base);
    float4 xi4 = *(const float4*)(xi + base);
    float ar[4] = {xr4.x, xr4.y, xr4.z, xr4.w};
    float ai[4] = {xi4.x, xi4.y, xi4.z, xi4.w};

    float sr = ar[0] + ar[1] + ar[2] + ar[3];
    float si = ai[0] + ai[1] + ai[2] + ai[3];
#pragma unroll
    for (int o = 1; o < 64; o <<= 1) {
        sr += __shfl_xor(sr, o, 64);
        si += __shfl_xor(si, o, 64);
    }
    float mre = sr * (1.f / DIM_), mim = si * (1.f / DIM_);

    float drv[4], div[4];
    float vr = 0.f, vi = 0.f;
#pragma unroll
    for (int j = 0; j < 4; j++) {
        drv[j] = ar[j] - mre;
        div[j] = ai[j] - mim;
        vr += drv[j] * drv[j];
        vi += div[j] * div[j];
    }
#pragma unroll
    for (int o = 1; o < 64; o <<= 1) {
        vr += __shfl_xor(vr, o, 64);
        vi += __shfl_xor(vi, o, 64);
    }
    float c = vr * (1.f / DIM_) + EPS_;
    float d = vi * (1.f / DIM_);
    float r = sqrtf(c * c + d * d);
    float sre = sqrtf(0.5f * (r + c));
    float sim = sqrtf(fmaxf(0.5f * (r - c), 0.f));
    float inv = 1.f / r;

    int wc = lane * 4;
    float4 wr4 = *(const float4*)(wr + wc);
    float4 wi4 = *(const float4*)(wi + wc);
    float4 br4 = *(const float4*)(br + wc);
    float4 bi4 = *(const float4*)(bi + wc);
    float wrv[4] = {wr4.x, wr4.y, wr4.z, wr4.w};
    float wiv[4] = {wi4.x, wi4.y, wi4.z, wi4.w};
    float brv[4] = {br4.x, br4.y, br4.z, br4.w};
    float biv[4] = {bi4.x, bi4.y, bi4.z, bi4.w};

    float orr[4], oii[4];
    unsigned short rh[4], rl[4], ih[4], il[4];
#pragma unroll
    for (int j = 0; j < 4; j++) {
        float nr = (drv[j] * sre + div[j] * sim) * inv;
        float ni = (div[j] * sre - drv[j] * sim) * inv;
        orr[j] = wrv[j] * nr - wiv[j] * ni + brv[j];
        oii[j] = wrv[j] * ni + wiv[j] * nr + biv[j];
        split2(orr[j], rh[j], rl[j]);
        split2(oii[j], ih[j], il[j]);
    }
    *(float4*)(outr + base) = make_float4(orr[0], orr[1], orr[2], orr[3]);
    *(float4*)(outi + base) = make_float4(oii[0], oii[1], oii[2], oii[3]);
    *(ushort4*)(planes + 0 * (size_t)S + base) = make_ushort4(rh[0], rh[1], rh[2], rh[3]);
    *(ushort4*)(planes + 1 * (size_t)S + base) = make_ushort4(rl[0], rl[1], rl[2], rl[3]);
    *(ushort4*)(planes + 2 * (size_t)S + base) = make_ushort4(ih[0], ih[1], ih[2], ih[3]);
    *(ushort4*)(planes + 3 * (size_t)S + base) = make_ushort4(il[0], il[1], il[2], il[3]);
}

// ---------------- fused weight split (qkv + outw + ff in one dispatch) ----------------
__global__ void wsplit_all(const float* __restrict__ s0r, const float* __restrict__ s0i,
                           const float* __restrict__ s1r, const float* __restrict__ s1i,
                           const float* __restrict__ s2r, const float* __restrict__ s2i,
                           unsigned short* __restrict__ d0,
                           unsigned short* __restrict__ d1,
                           unsigned short* __restrict__ d2) {
    const int PER = DEPTH_ * 65536;
    int gid = blockIdx.x * 256 + threadIdx.x;
    int sel = gid / PER;
    int idx = gid - sel * PER;
    const float* wr = (sel == 0) ? s0r : (sel == 1) ? s1r : s2r;
    const float* wi = (sel == 0) ? s0i : (sel == 1) ? s1i : s2i;
    unsigned short* dst = (sel == 0) ? d0 : (sel == 1) ? d1 : d2;
    int l = idx >> 16, e = idx & 65535;
    unsigned short rh, rl, ih, il;
    split2(wr[idx], rh, rl);
    split2(wi[idx], ih, il);
    size_t base = (size_t)l * 4 * 65536;
    dst[base + 0 * 65536 + e] = rh;
    dst[base + 1 * 65536 + e] = rl;
    dst[base + 2 * 65536 + e] = ih;
    dst[base + 3 * 65536 + e] = il;
}

// ---------------- MFMA complex GEMM: 32x64 tile, 4 waves, LDS-staged B ----------------
// grid (M/32=64, 256/64=4), 256 threads. Wave w: rows (w&1)*16, col-tiles {(w>>1)*2, +1}.
// B (64 cols x 32 k x 4 planes per chunk) cooperatively staged in LDS, double-buffered,
// stored in lane-fragment order (slot = lane) -> store AND read are lane-linear, 0 conflicts.
// A fragments direct from global/L2 (16 rows per wave). One barrier per k-chunk.
// Per-element math and k-order identical to the 16x16 version -> bit-identical output.
template <int MODE>
__global__ __launch_bounds__(256)
void gemm_mfma(const unsigned short* __restrict__ Ap, int aStride,
               const unsigned short* __restrict__ Bp,
               unsigned short* __restrict__ wpo, unsigned short* __restrict__ wtpo,
               const float* __restrict__ biasR, const float* __restrict__ biasI,
               const float* resR, const float* resI,
               float* xoR, float* xoI, int S) {
    __shared__ short8 Bs[2][4][4][64];        // [buf][plane][nt][slot] = 32 KB
    const int K = 256;
    int tileM = blockIdx.x * 32, tileN = blockIdx.y * 64;
    int tid = threadIdx.x;
    int wave = tid >> 6, lane = tid & 63;
    int m16 = lane & 15, quad = lane >> 4;
    int rowHalf = wave & 1, ntBase = (wave >> 1) * 2;
    int rowA = tileM + rowHalf * 16 + m16;

    f32x4 accP[2], accN[2], accIa[2], accIb[2];
#pragma unroll
    for (int j = 0; j < 2; j++) {
        accP[j] = (f32x4){0,0,0,0}; accN[j] = (f32x4){0,0,0,0};
        accIa[j] = (f32x4){0,0,0,0}; accIb[j] = (f32x4){0,0,0,0};
    }

    // loader role: plane p = wave, slot s = lane (covers all 4 planes x 64 slots)
    int ls = lane;
    int lrow = tileN + (ls & 15);             // + nt*16
    int lk0 = (ls >> 4) * 8;

    for (int k0 = 0; k0 < 256; k0 += 32) {
        int buf = (k0 >> 5) & 1;
        // cooperative B stage: fragment for (plane=wave, nt, m16=s&15, quad=s>>4) -> slot s
#pragma unroll
        for (int nt = 0; nt < 4; nt++) {
            Bs[buf][wave][nt][ls] =
                *(const short8*)(Bp + (size_t)wave * 65536 + (size_t)(lrow + nt * 16) * K + k0 + lk0);
        }
        // A fragments (direct), same content/order as 16x16 version
        int kb = k0 + quad * 8;
        short8 a[4];
#pragma unroll
        for (int p = 0; p < 4; p++)
            a[p] = *(const short8*)(Ap + (size_t)p * aStride + (size_t)rowA * K + kb);
        __syncthreads();
#pragma unroll
        for (int j = 0; j < 2; j++) {
            int nt = ntBase + j;
            short8 b[4];
#pragma unroll
            for (int p = 0; p < 4; p++)
                b[p] = Bs[buf][p][nt][lane];
            accP[j]  = mfma16(a[0], b[0], accP[j]);
            accP[j]  = mfma16(a[0], b[1], accP[j]);
            accP[j]  = mfma16(a[1], b[0], accP[j]);
            accN[j]  = mfma16(a[2], b[2], accN[j]);
            accN[j]  = mfma16(a[2], b[3], accN[j]);
            accN[j]  = mfma16(a[3], b[2], accN[j]);
            accIa[j] = mfma16(a[0], b[2], accIa[j]);
            accIa[j] = mfma16(a[0], b[3], accIa[j]);
            accIa[j] = mfma16(a[1], b[2], accIa[j]);
            accIb[j] = mfma16(a[2], b[0], accIb[j]);
            accIb[j] = mfma16(a[2], b[1], accIb[j]);
            accIb[j] = mfma16(a[3], b[0], accIb[j]);
        }
    }

#pragma unroll
    for (int j = 0; j < 2; j++) {
        int nt = ntBase + j;
#pragma unroll
        for (int r = 0; r < 4; r++) {
            int row = tileM + rowHalf * 16 + quad * 4 + r;
            int col = tileN + nt * 16 + m16;
            size_t g = (size_t)row * 256 + col;
            float vr = accP[j][r] - accN[j][r];
            float vi = accIa[j][r] + accIb[j][r];
            if (MODE == 1) {
                unsigned short h0, h1, h2, h3;
                split2(vr, h0, h1);
                split2(vi, h2, h3);
                size_t tidx = ((size_t)(row >> 10) * 256 + col) * 1024 + (row & 1023);
                wpo[0 * (size_t)S + g] = h0;
                wpo[1 * (size_t)S + g] = h1;
                wpo[2 * (size_t)S + g] = h2;
                wpo[3 * (size_t)S + g] = h3;
                wtpo[0 * (size_t)S + tidx] = h0;
                wtpo[1 * (size_t)S + tidx] = h1;
                wtpo[2 * (size_t)S + tidx] = h2;
                wtpo[3 * (size_t)S + tidx] = h3;
            } else if (MODE == 2) {
                xoR[g] = vr + biasR[col] + resR[g];
                xoI[g] = vi + biasI[col] + resI[g];
            } else {
                float zr = resR[g] + STEP_ * vr - STEP_ * LAMBD_;
                float zi = resI[g] + STEP_ * vi;
                xoR[g] = fmaxf(zr, 0.f);
                xoI[g] = fmaxf(zi, 0.f);
            }
        }
    }
}

// ---------------- MFMA flash attention: split-K across blocks, low-VGPR (FROZEN r13) ----------------
__global__ __launch_bounds__(256, 2)
void attn_mfma(const unsigned short* __restrict__ wp,
               const unsigned short* __restrict__ wtp,
               float* __restrict__ Op, float* __restrict__ ml, int S) {
    __shared__ unsigned int ShBuf[6336];
    __shared__ float mlbuf[4][64][2];

    int tid = threadIdx.x;
    int wave = tid >> 6, lane = tid & 63;
    int m16 = lane & 15, quad = lane >> 4;
    int zz = blockIdx.x, bb = zz >> 2, hh = zz & 3;
    int q0 = blockIdx.y * 16;
    int kz = blockIdx.z;

    short8 qf[4][2];
    {
        size_t qbase = (size_t)(bb * N_ + q0 + m16) * INNER_ + hh * DHEAD_;
#pragma unroll
        for (int p = 0; p < 4; p++)
#pragma unroll
            for (int kc = 0; kc < 2; kc++)
                qf[p][kc] = *(const short8*)(wp + (size_t)p * S + qbase + kc * 32 + quad * 8);
    }

    float mrow = -1e30f, lrow = 0.f;
    f32x4 Oa[4][2];
#pragma unroll
    for (int ni = 0; ni < 4; ni++) { Oa[ni][0] = (f32x4){0,0,0,0}; Oa[ni][1] = (f32x4){0,0,0,0}; }

    unsigned int* prbu = ShBuf + wave * 1056;

    for (int t = 0; t < 2; t++) {
        int kt = kz * 8 + wave + 4 * t;

        f32x4 sr[4], si[4];
#pragma unroll
        for (int ni = 0; ni < 4; ni++) { sr[ni] = (f32x4){0,0,0,0}; si[ni] = (f32x4){0,0,0,0}; }
#pragma unroll
        for (int ni = 0; ni < 4; ni++) {
            size_t kbase = (size_t)(bb * N_ + kt * 64 + ni * 16 + m16) * INNER_ + hh * DHEAD_;
            short8 kf[4][2];
#pragma unroll
            for (int p = 0; p < 4; p++)
#pragma unroll
                for (int kc = 0; kc < 2; kc++)
                    kf[p][kc] = *(const short8*)(wp + (size_t)p * S + kbase + kc * 32 + quad * 8);
#pragma unroll
            for (int kc = 0; kc < 2; kc++) {
                short8 nki_h = neg8(kf[2][kc]);
                short8 nki_l = neg8(kf[3][kc]);
                f32x4 r = sr[ni], im = si[ni];
                r  = mfma16(kf[0][kc], qf[0][kc], r);
                r  = mfma16(kf[0][kc], qf[1][kc], r);
                r  = mfma16(kf[1][kc], qf[0][kc], r);
                r  = mfma16(kf[2][kc], qf[2][kc], r);
                r  = mfma16(kf[2][kc], qf[3][kc], r);
                r  = mfma16(kf[3][kc], qf[2][kc], r);
                im = mfma16(kf[0][kc], qf[2][kc], im);
                im = mfma16(kf[0][kc], qf[3][kc], im);
                im = mfma16(kf[1][kc], qf[2][kc], im);
                im = mfma16(nki_h, qf[0][kc], im);
                im = mfma16(nki_h, qf[1][kc], im);
                im = mfma16(nki_l, qf[0][kc], im);
                sr[ni] = r; si[ni] = im;
            }
        }

        float mag[4][4], srs[4][4], sis[4][4];
        float mx = -1e30f;
#pragma unroll
        for (int ni = 0; ni < 4; ni++)
#pragma unroll
            for (int r = 0; r < 4; r++) {
                float a = sr[ni][r] * SCALE_, b = si[ni][r] * SCALE_;
                srs[ni][r] = a; sis[ni][r] = b;
                float mg = sqrtf(a * a + b * b);
                mag[ni][r] = mg;
                mx = fmaxf(mx, mg);
            }
        mx = fmaxf(mx, __shfl_xor(mx, 16, 64));
        mx = fmaxf(mx, __shfl_xor(mx, 32, 64));
        float newm = fmaxf(mrow, mx);
        float alpha = __expf(mrow - newm);
        mrow = newm;
        float psum = 0.f;
#pragma unroll
        for (int ni = 0; ni < 4; ni++)
#pragma unroll
            for (int r = 0; r < 4; r++) {
                float p = __expf(mag[ni][r] - newm);
                psum += p;
                float sc = (mag[ni][r] > 0.f) ? (p / mag[ni][r]) : 0.f;
                float pr = (mag[ni][r] > 0.f) ? srs[ni][r] * sc : p;
                float pi = sis[ni][r] * sc;
                int key = ni * 16 + quad * 4 + r;
                prbu[m16 * 66 + key] = ((unsigned)bf16_rne(pi) << 16) | bf16_rne(pr);
            }
        psum += __shfl_xor(psum, 16, 64);
        psum += __shfl_xor(psum, 32, 64);
        lrow = lrow * alpha + psum;
#pragma unroll
        for (int ni = 0; ni < 4; ni++)
#pragma unroll
            for (int r = 0; r < 4; r++) { Oa[ni][0][r] *= alpha; Oa[ni][1][r] *= alpha; }

        short8 prh[2], pih[2], nih[2];
#pragma unroll
        for (int kc = 0; kc < 2; kc++) {
            short8 x, y;
#pragma unroll
            for (int j = 0; j < 8; j++) {
                unsigned val = prbu[m16 * 66 + kc * 32 + quad * 8 + j];
                x[j] = (short)(val & 0xffffu);
                y[j] = (short)(val >> 16);
            }
            prh[kc] = x; pih[kc] = y; nih[kc] = neg8(y);
        }

#pragma unroll
        for (int ni = 0; ni < 4; ni++) {
            size_t vbase = (size_t)(bb * INNER_ + hh * DHEAD_ + ni * 16 + m16) * N_ + kt * 64;
            short8 vr0 = *(const short8*)(wtp + 0 * (size_t)S + vbase + quad * 8);
            short8 vr1 = *(const short8*)(wtp + 0 * (size_t)S + vbase + 32 + quad * 8);
            short8 vi0 = *(const short8*)(wtp + 2 * (size_t)S + vbase + quad * 8);
            short8 vi1 = *(const short8*)(wtp + 2 * (size_t)S + vbase + 32 + quad * 8);
            f32x4 orv = Oa[ni][0], oiv = Oa[ni][1];
            orv = mfma16(vr0, prh[0], orv);
            orv = mfma16(vi0, nih[0], orv);
            orv = mfma16(vr1, prh[1], orv);
            orv = mfma16(vi1, nih[1], orv);
            oiv = mfma16(vr0, pih[0], oiv);
            oiv = mfma16(vi0, prh[0], oiv);
            oiv = mfma16(vr1, pih[1], oiv);
            oiv = mfma16(vi1, prh[1], oiv);
            Oa[ni][0] = orv; Oa[ni][1] = oiv;
        }
    }

    float* Obuf = (float*)ShBuf;
    __syncthreads();
    if (wave != 0) {
        float* mb = Obuf + (wave - 1) * 2112 + lane * 33;
#pragma unroll
        for (int ni = 0; ni < 4; ni++)
#pragma unroll
            for (int r = 0; r < 4; r++) {
                mb[ni * 8 + r]     = Oa[ni][0][r];
                mb[ni * 8 + 4 + r] = Oa[ni][1][r];
            }
        mlbuf[wave][lane][0] = mrow;
        mlbuf[wave][lane][1] = lrow;
    }
    __syncthreads();
    if (wave == 0) {
        float mm = mrow;
#pragma unroll
        for (int w = 1; w < 4; w++) mm = fmaxf(mm, mlbuf[w][lane][0]);
        float a0 = __expf(mrow - mm);
        float ltot = a0 * lrow;
        float aw[3];
#pragma unroll
        for (int w = 1; w < 4; w++) {
            aw[w - 1] = __expf(mlbuf[w][lane][0] - mm);
            ltot += aw[w - 1] * mlbuf[w][lane][1];
        }
        size_t obase = (size_t)(bb * N_ + q0 + m16) * INNER_ + hh * DHEAD_;
        float* opr = Op + (size_t)kz * 2 * S;
        float* opi = opr + S;
#pragma unroll
        for (int ni = 0; ni < 4; ni++)
#pragma unroll
            for (int r = 0; r < 4; r++) {
                float vr = a0 * Oa[ni][0][r];
                float vi = a0 * Oa[ni][1][r];
#pragma unroll
                for (int w = 1; w < 4; w++) {
                    vr += aw[w - 1] * Obuf[(w - 1) * 2112 + lane * 33 + ni * 8 + r];
                    vi += aw[w - 1] * Obuf[(w - 1) * 2112 + lane * 33 + ni * 8 + 4 + r];
                }
                size_t o = obase + ni * 16 + quad * 4 + r;
                opr[o] = vr;
                opi[o] = vi;
            }
        if (quad == 0) {
            int row = bb * N_ + q0 + m16;
            ((float2*)ml)[kz * 8192 + row * 4 + hh] = make_float2(mm, ltot);
        }
    }
}

// ---------------- merge the two key-halves, emit 4 bf16 planes ----------------
__global__ void attn_merge(const float* __restrict__ Op, const float* __restrict__ ml,
                           unsigned short* __restrict__ aop, int S) {
    int idx = blockIdx.x * 256 + threadIdx.x;
    int row = idx >> 8;
    int hh = (idx >> 6) & 3;
    float2 ml0 = ((const float2*)ml)[row * 4 + hh];
    float2 ml1 = ((const float2*)ml)[8192 + row * 4 + hh];
    float mm = fmaxf(ml0.x, ml1.x);
    float a0 = __expf(ml0.x - mm), a1 = __expf(ml1.x - mm);
    float invl = 1.f / (a0 * ml0.y + a1 * ml1.y);
    float vr = (a0 * Op[idx] + a1 * Op[2 * (size_t)S + idx]) * invl;
    float vi = (a0 * Op[(size_t)S + idx] + a1 * Op[3 * (size_t)S + idx]) * invl;
    unsigned short h0, h1, h2, h3;
    split2(vr, h0, h1);
    split2(vi, h2, h3);
    aop[0 * (size_t)S + idx] = h0;
    aop[1 * (size_t)S + idx] = h1;
    aop[2 * (size_t)S + idx] = h2;
    aop[3 * (size_t)S + idx] = h3;
}

// ---------------- output pack (fallback only) ----------------
__global__ void pack_real(const float* __restrict__ xr, float* __restrict__ out, int cap) {
    int idx = blockIdx.x * 256 + threadIdx.x;
    if (idx < cap) out[idx] = xr[idx];
}

// ---------------- host orchestration ----------------
extern "C" void kernel_launch(void* const* d_in, const int* in_sizes, int n_in,
                              void* d_out, int out_size, void* d_ws, size_t ws_size,
                              hipStream_t stream) {
    const float* in_xre = (const float*)d_in[0];
    const float* in_xim = (const float*)d_in[1];
    const float* ln1wr = (const float*)d_in[2];
    const float* ln1wi = (const float*)d_in[3];
    const float* ln1br = (const float*)d_in[4];
    const float* ln1bi = (const float*)d_in[5];
    const float* qkvr  = (const float*)d_in[6];
    const float* qkvi  = (const float*)d_in[7];
    const float* outwr = (const float*)d_in[8];
    const float* outwi = (const float*)d_in[9];
    const float* outbr = (const float*)d_in[10];
    const float* outbi = (const float*)d_in[11];
    const float* ln2wr = (const float*)d_in[12];
    const float* ln2wi = (const float*)d_in[13];
    const float* ln2br = (const float*)d_in[14];
    const float* ln2bi = (const float*)d_in[15];
    const float* ffr   = (const float*)d_in[16];
    const float* ffi   = (const float*)d_in[17];

    const size_t S = (size_t)B_ * N_ * DIM_;          // 524288
    const int    Si = (int)S;

    float* ws  = (float*)d_ws;
    float* xre = ws;            float* xim = xre + S;
    float* xnr = xim + S;       float* xni = xnr + S;
    float* Opart = xni + S;                              // 4*S fp32 (2 halves x re/im)
    float* mlb   = Opart + 4 * S;                        // 2*8192 float2 = 32768 floats

    unsigned short* xnp   = (unsigned short*)(mlb + 32768);
    unsigned short* aop   = xnp + 4 * S;
    unsigned short* wpb   = aop + 4 * S;
    unsigned short* wtpb  = wpb + 4 * S;
    unsigned short* qkvp  = wtpb + 4 * S;
    unsigned short* outwp = qkvp + (size_t)DEPTH_ * 4 * 65536;
    unsigned short* ffp   = outwp + (size_t)DEPTH_ * 4 * 65536;

    wsplit_all<<<3 * DEPTH_ * 65536 / 256, 256, 0, stream>>>(
        qkvr, qkvi, outwr, outwi, ffr, ffi, qkvp, outwp, ffp);

    const int MR = B_ * N_;
    dim3 gGemm(MR / 32, INNER_ / 64);       // (64, 4): 256 blocks, 32x64 tiles
    dim3 gAttn(B_ * HEADS_, N_ / 16, 2);    // (8, 64, 2): x = (b,h) -> XCD-local K/V
    int eBlocks = (int)(S / 256);

    bool directOut = (out_size >= (int)(2 * S));
    float* foutR = directOut ? (float*)d_out : xre;
    float* foutI = directOut ? (float*)d_out + S : xim;

    for (int l = 0; l < DEPTH_; l++) {
        const float* xinR = (l == 0) ? in_xre : xre;
        const float* xinI = (l == 0) ? in_xim : xim;

        ln_kernel<<<MR, 64, 0, stream>>>(xinR, xinI,
            ln1wr + l * DIM_, ln1wi + l * DIM_, ln1br + l * DIM_, ln1bi + l * DIM_,
            xnr, xni, xnp, Si);

        gemm_mfma<1><<<gGemm, 256, 0, stream>>>(xnp, Si, qkvp + (size_t)l * 4 * 65536,
            wpb, wtpb, nullptr, nullptr, nullptr, nullptr, nullptr, nullptr, Si);

        attn_mfma<<<gAttn, 256, 0, stream>>>(wpb, wtpb, Opart, mlb, Si);
        attn_merge<<<eBlocks, 256, 0, stream>>>(Opart, mlb, aop, Si);

        gemm_mfma<2><<<gGemm, 256, 0, stream>>>(aop, Si, outwp + (size_t)l * 4 * 65536,
            nullptr, nullptr, outbr + l * DIM_, outbi + l * DIM_, xinR, xinI, xre, xim, Si);

        ln_kernel<<<MR, 64, 0, stream>>>(xre, xim,
            ln2wr + l * DIM_, ln2wi + l * DIM_, ln2br + l * DIM_, ln2bi + l * DIM_,
            xnr, xni, xnp, Si);

        float* oR = (l == DEPTH_ - 1) ? foutR : xre;
        float* oI = (l == DEPTH_ - 1) ? foutI : xim;
        gemm_mfma<3><<<gGemm, 256, 0, stream>>>(xnp, Si, ffp + (size_t)l * 4 * 65536,
            nullptr, nullptr, nullptr, nullptr, xnr, xni, oR, oI, Si);
    }

    if (!directOut) {
        pack_real<<<eBlocks, 256, 0, stream>>>(xre, (float*)d_out, out_size);
    }
}